// Round 1
// baseline (1553.641 us; speedup 1.0000x reference)
//
#include <hip/hip_runtime.h>
#include <hip/hip_bf16.h>

#define BATCH 4
#define CCH 256
#define TLEN 8192
#define LAYERS 10
#define BCT (BATCH*CCH*TLEN)   // 8,388,608 elements

typedef __attribute__((ext_vector_type(8))) short bf16x8;
typedef __attribute__((ext_vector_type(4))) float f32x4;

__device__ __forceinline__ unsigned short f2b(float f) {
  union { float f; unsigned u; } v; v.f = f;
  unsigned r = (v.u + 0x7FFFu + ((v.u >> 16) & 1u)) >> 16;
  return (unsigned short)r;
}
__device__ __forceinline__ float b2f(unsigned short h) {
  union { unsigned u; float f; } v; v.u = ((unsigned)h) << 16;
  return v.f;
}

// ---------------------------------------------------------------------------
// Weight repack: wconv [L][512][256][3] fp32 -> Wb [L][3][512][256] bf16
//                wout  [L][256][256]    fp32 -> Wob (same layout)     bf16
// ---------------------------------------------------------------------------
__global__ void repack_w(const float* __restrict__ wc, const float* __restrict__ wo,
                         unsigned short* __restrict__ Wb, unsigned short* __restrict__ Wob) {
  size_t g = (size_t)blockIdx.x * 256 + threadIdx.x;
  const size_t NA = (size_t)LAYERS * 3 * 512 * 256;
  if (g < NA) {
    int c   = (int)(g & 255);
    int o   = (int)((g >> 8) & 511);
    int rest = (int)(g >> 17);          // l*3 + tap
    int tap = rest % 3, l = rest / 3;
    Wb[g] = f2b(wc[(((size_t)l * 512 + o) * 256 + c) * 3 + tap]);
  } else {
    size_t g2 = g - NA;
    if (g2 < (size_t)LAYERS * 256 * 256) Wob[g2] = f2b(wo[g2]);
  }
}

// ---------------------------------------------------------------------------
// Transpose input [B][C][T] fp32 -> xT [B][T][C] fp32
// ---------------------------------------------------------------------------
__global__ void transpose_in(const float* __restrict__ in, float* __restrict__ xT) {
  __shared__ float tile[32][33];
  const int tid = threadIdx.x;
  const int t0 = blockIdx.x * 32, c0 = blockIdx.y * 32, b = blockIdx.z;
#pragma unroll
  for (int q = 0; q < 4; ++q) {
    int e = tid + 256 * q; int r = e >> 5, cc = e & 31;   // r = c-local, cc = t-local
    tile[r][cc] = in[((size_t)b * CCH + c0 + r) * TLEN + t0 + cc];
  }
  __syncthreads();
#pragma unroll
  for (int q = 0; q < 4; ++q) {
    int e = tid + 256 * q; int r = e >> 5, cc = e & 31;   // r = t-local, cc = c-local
    xT[((size_t)b * TLEN + t0 + r) * CCH + c0 + cc] = tile[cc][r];
  }
}

// ---------------------------------------------------------------------------
// Final: out[B][C][T] = xT[B][T][C] + hT(bf16)[B][T][C]   (last layer residual)
// ---------------------------------------------------------------------------
__global__ void final_addT(const float* __restrict__ xT, const unsigned short* __restrict__ hT,
                           float* __restrict__ out) {
  __shared__ float tile[32][33];
  const int tid = threadIdx.x;
  const int t0 = blockIdx.x * 32, c0 = blockIdx.y * 32, b = blockIdx.z;
#pragma unroll
  for (int q = 0; q < 4; ++q) {
    int e = tid + 256 * q; int r = e >> 5, cc = e & 31;   // r = t-local, cc = c-local
    size_t idx = ((size_t)b * TLEN + t0 + r) * CCH + c0 + cc;
    tile[r][cc] = xT[idx] + b2f(hT[idx]);
  }
  __syncthreads();
#pragma unroll
  for (int q = 0; q < 4; ++q) {
    int e = tid + 256 * q; int r = e >> 5, cc = e & 31;   // r = c-local, cc = t-local
    out[((size_t)b * CCH + c0 + r) * TLEN + t0 + cc] = tile[cc][r];
  }
}

// ---------------------------------------------------------------------------
// Dilated causal conv + gate.  Computes Z^T tile (m=time, n=channel).
// Block tile: 128 t  x  (64 top + 64 bottom channels, interleaved by 16).
// Writes: hT [B][T][C] bf16  and  skip [B][C][T] fp32.
// ---------------------------------------------------------------------------
__global__ __launch_bounds__(256, 2)
void conv_gate_kernel(const float* __restrict__ xT,          // [B][T][C] fp32
                      const unsigned short* __restrict__ Wb, // [3][512][256] bf16, this layer
                      const float* __restrict__ bias,        // [512] fp32
                      unsigned short* __restrict__ hT,       // [B][T][C] bf16
                      float* __restrict__ skip,              // [B][C][T] fp32, this layer
                      int d) {
  __shared__ unsigned short As[128 * 40];  // [m=t][k] , rows padded 32->40
  __shared__ unsigned short Bs[128 * 40];  // [n=ch][k]

  const int tid  = threadIdx.x;
  const int lane = tid & 63;
  const int wv   = tid >> 6;
  const int wm   = wv & 1, wn = wv >> 1;
  const int col  = lane & 15, quad = lane >> 4;

  const int t0 = blockIdx.x * 128;
  const int o0 = blockIdx.y * 64;
  const int b  = blockIdx.z;

  f32x4 acc[4][4];
  const f32x4 zero = {0.f, 0.f, 0.f, 0.f};
#pragma unroll
  for (int i = 0; i < 4; ++i)
#pragma unroll
    for (int j = 0; j < 4; ++j) acc[i][j] = zero;

  for (int tap = 0; tap < 3; ++tap) {
    const int s = (2 - tap) * d;                         // causal shift: x[t - s]
    const unsigned short* Wtap = Wb + (size_t)tap * 512 * 256;
    for (int c0 = 0; c0 < 256; c0 += 32) {
      __syncthreads();
      // ---- stage A: As[row][kk] = bf16(xT[b][t0+row-s][c0+kk]), 128x32
#pragma unroll
      for (int q = 0; q < 4; ++q) {
        int e = tid + 256 * q;
        int row = e >> 3, f4 = e & 7;
        int trow = t0 + row - s;
        ushort4 w4;
        if (trow >= 0) {
          const float4 v = *(const float4*)&xT[((size_t)b * TLEN + trow) * CCH + c0 + f4 * 4];
          w4.x = f2b(v.x); w4.y = f2b(v.y); w4.z = f2b(v.z); w4.w = f2b(v.w);
        } else {
          w4.x = 0; w4.y = 0; w4.z = 0; w4.w = 0;
        }
        *(ushort4*)&As[row * 40 + f4 * 4] = w4;
      }
      // ---- stage B: Bs[row][kk] = Wb[tap][ch(row)][c0+kk], 128x32
      //      row -> channel: 16-wide groups alternating top/bottom
#pragma unroll
      for (int q = 0; q < 2; ++q) {
        int e = tid + 256 * q;
        int row = e >> 2, c8 = e & 3;
        int grp = row >> 4, within = row & 15;
        int ch = o0 + ((grp >> 1) << 4) + within + ((grp & 1) << 8);
        *(int4*)&Bs[row * 40 + c8 * 8] = *(const int4*)&Wtap[(size_t)ch * 256 + c0 + c8 * 8];
      }
      __syncthreads();
      // ---- 16 MFMA on the 2x2 wave grid, wave tile 64x64
      const int k0 = quad * 8;
      bf16x8 af[4], bfv[4];
#pragma unroll
      for (int mf = 0; mf < 4; ++mf)
        af[mf] = *(const bf16x8*)&As[(wm * 64 + mf * 16 + col) * 40 + k0];
#pragma unroll
      for (int nf = 0; nf < 4; ++nf)
        bfv[nf] = *(const bf16x8*)&Bs[(wn * 64 + nf * 16 + col) * 40 + k0];
#pragma unroll
      for (int mf = 0; mf < 4; ++mf)
#pragma unroll
        for (int nf = 0; nf < 4; ++nf)
          acc[mf][nf] = __builtin_amdgcn_mfma_f32_16x16x32_bf16(af[mf], bfv[nf], acc[mf][nf], 0, 0, 0);
    }
  }

  // ---- epilogue: bias, gate, store hT (bf16, [t][c]) and skip (fp32, [c][t])
#pragma unroll
  for (int mf = 0; mf < 4; ++mf) {
    const int tb = t0 + wm * 64 + mf * 16 + quad * 4;
#pragma unroll
    for (int p = 0; p < 2; ++p) {
      const int pair = wn * 2 + p;
      const int ch = o0 + pair * 16 + col;       // gated output channel (0..255)
      const float btop = bias[ch];
      const float bbot = bias[ch + 256];
      f32x4 zt = acc[mf][2 * p];
      f32x4 zb = acc[mf][2 * p + 1];
      float hr[4];
#pragma unroll
      for (int r = 0; r < 4; ++r) {
        float ztv = zt[r] + btop;
        float zbv = zb[r] + bbot;
        float h = tanhf(ztv) * (1.f / (1.f + __expf(-zbv)));
        hr[r] = h;
        hT[((size_t)b * TLEN + tb + r) * CCH + ch] = f2b(h);
      }
      float4 hv; hv.x = hr[0]; hv.y = hr[1]; hv.z = hr[2]; hv.w = hr[3];
      *(float4*)&skip[((size_t)b * CCH + ch) * TLEN + tb] = hv;
    }
  }
}

// ---------------------------------------------------------------------------
// 1x1 transform + residual (in-place on xT):
//   xT[b][t][o] += sum_c Wo[o][c] * h[b][c][t] + bout[o]
// ---------------------------------------------------------------------------
__global__ __launch_bounds__(256, 2)
void onexone_kernel(const unsigned short* __restrict__ hT,  // [B][T][C] bf16
                    const unsigned short* __restrict__ Wo,  // [256][256] bf16, this layer
                    const float* __restrict__ bias,         // [256]
                    float* __restrict__ xT) {               // [B][T][C] fp32, in-place
  __shared__ unsigned short As[128 * 40];
  __shared__ unsigned short Bs[128 * 40];

  const int tid  = threadIdx.x;
  const int lane = tid & 63;
  const int wv   = tid >> 6;
  const int wm   = wv & 1, wn = wv >> 1;
  const int col  = lane & 15, quad = lane >> 4;

  const int t0 = blockIdx.x * 128;
  const int o0 = blockIdx.y * 128;
  const int b  = blockIdx.z;

  f32x4 acc[4][4];
  const f32x4 zero = {0.f, 0.f, 0.f, 0.f};
#pragma unroll
  for (int i = 0; i < 4; ++i)
#pragma unroll
    for (int j = 0; j < 4; ++j) acc[i][j] = zero;

  for (int c0 = 0; c0 < 256; c0 += 32) {
    __syncthreads();
#pragma unroll
    for (int q = 0; q < 2; ++q) {     // A from hT (already bf16)
      int e = tid + 256 * q;
      int row = e >> 2, c8 = e & 3;
      *(int4*)&As[row * 40 + c8 * 8] =
          *(const int4*)&hT[((size_t)b * TLEN + t0 + row) * CCH + c0 + c8 * 8];
    }
#pragma unroll
    for (int q = 0; q < 2; ++q) {     // B from Wo
      int e = tid + 256 * q;
      int row = e >> 2, c8 = e & 3;
      *(int4*)&Bs[row * 40 + c8 * 8] =
          *(const int4*)&Wo[(size_t)(o0 + row) * 256 + c0 + c8 * 8];
    }
    __syncthreads();
    const int k0 = quad * 8;
    bf16x8 af[4], bfv[4];
#pragma unroll
    for (int mf = 0; mf < 4; ++mf)
      af[mf] = *(const bf16x8*)&As[(wm * 64 + mf * 16 + col) * 40 + k0];
#pragma unroll
    for (int nf = 0; nf < 4; ++nf)
      bfv[nf] = *(const bf16x8*)&Bs[(wn * 64 + nf * 16 + col) * 40 + k0];
#pragma unroll
    for (int mf = 0; mf < 4; ++mf)
#pragma unroll
      for (int nf = 0; nf < 4; ++nf)
        acc[mf][nf] = __builtin_amdgcn_mfma_f32_16x16x32_bf16(af[mf], bfv[nf], acc[mf][nf], 0, 0, 0);
  }

#pragma unroll
  for (int mf = 0; mf < 4; ++mf) {
    const int tb = t0 + wm * 64 + mf * 16 + quad * 4;
#pragma unroll
    for (int nf = 0; nf < 4; ++nf) {
      const int ch = o0 + wn * 64 + nf * 16 + col;
      const float bo = bias[ch];
#pragma unroll
      for (int r = 0; r < 4; ++r) {
        size_t idx = ((size_t)b * TLEN + tb + r) * CCH + ch;
        xT[idx] = xT[idx] + acc[mf][nf][r] + bo;
      }
    }
  }
}

// ---------------------------------------------------------------------------
extern "C" void kernel_launch(void* const* d_in, const int* in_sizes, int n_in,
                              void* d_out, int out_size, void* d_ws, size_t ws_size,
                              hipStream_t stream) {
  const float* input = (const float*)d_in[0];
  const float* wconv = (const float*)d_in[1];
  const float* bconv = (const float*)d_in[2];
  const float* wout  = (const float*)d_in[3];
  const float* bout  = (const float*)d_in[4];
  float* out   = (float*)d_out;
  float* skips = out + (size_t)BCT;        // [L][B][C][T]

  char* ws = (char*)d_ws;
  float*          xT  = (float*)ws;                                        // BCT fp32
  unsigned short* hT  = (unsigned short*)(ws + (size_t)BCT * 4);           // BCT bf16
  unsigned short* Wb  = (unsigned short*)(ws + (size_t)BCT * 4 + (size_t)BCT * 2);
  unsigned short* Wob = Wb + (size_t)LAYERS * 3 * 512 * 256;

  static const int dil[LAYERS] = {1, 2, 4, 8, 16, 32, 64, 128, 256, 512};

  repack_w<<<17920, 256, 0, stream>>>(wconv, wout, Wb, Wob);
  transpose_in<<<dim3(TLEN / 32, CCH / 32, BATCH), 256, 0, stream>>>(input, xT);

  for (int l = 0; l < LAYERS; ++l) {
    conv_gate_kernel<<<dim3(TLEN / 128, 4, BATCH), 256, 0, stream>>>(
        xT, Wb + (size_t)l * 3 * 512 * 256, bconv + (size_t)l * 512,
        hT, skips + (size_t)l * BCT, dil[l]);
    if (l < LAYERS - 1) {
      onexone_kernel<<<dim3(TLEN / 128, 2, BATCH), 256, 0, stream>>>(
          hT, Wob + (size_t)l * 256 * 256, bout + (size_t)l * 256, xT);
    } else {
      final_addT<<<dim3(TLEN / 32, CCH / 32, BATCH), 256, 0, stream>>>(xT, hT, out);
    }
  }
}

// Round 2
// 1042.044 us; speedup vs baseline: 1.4910x; 1.4910x over previous
//
#include <hip/hip_runtime.h>
#include <hip/hip_bf16.h>

#define BATCH 4
#define CCH 256
#define TLEN 8192
#define LAYERS 10
#define BCT (BATCH*CCH*TLEN)   // 8,388,608 elements
#define TPAD 1024              // causal zero-pad rows per batch (max shift = 2*512)
#define TROWS (TPAD + TLEN)    // 9216

typedef __attribute__((ext_vector_type(8))) short bf16x8;
typedef __attribute__((ext_vector_type(4))) float f32x4;

__device__ __forceinline__ unsigned short f2b(float f) {
  union { float f; unsigned u; } v; v.f = f;
  unsigned r = (v.u + 0x7FFFu + ((v.u >> 16) & 1u)) >> 16;
  return (unsigned short)r;
}
__device__ __forceinline__ float b2f(unsigned short h) {
  union { unsigned u; float f; } v; v.u = ((unsigned)h) << 16;
  return v.f;
}

// async global->LDS, 16 B per lane; lds base must be wave-uniform,
// lane i's data lands at lds + i*16 (m104/m108 semantics).
__device__ __forceinline__ void gload16(const void* g, void* l) {
  __builtin_amdgcn_global_load_lds((__attribute__((address_space(1))) void*)g,
                                   (__attribute__((address_space(3))) void*)l, 16, 0, 0);
}

__device__ __forceinline__ float fast_tanh(float x) {
  float a = fabsf(x);
  float e = __expf(-2.f * a);                       // in (0,1]
  float th = (1.f - e) * __builtin_amdgcn_rcpf(1.f + e);
  return copysignf(th, x);
}
__device__ __forceinline__ float fast_sigmoid(float x) {
  return __builtin_amdgcn_rcpf(1.f + __expf(-x));
}

// ---------------------------------------------------------------------------
// Weight repack:
//  wconv [L][512][256][3] fp32 -> Wb [L][3][4 yblk][128 row][256 c] bf16,
//    rows pre-interleaved into the conv kernel's gate-pairing order:
//    ch(y,row) = y*64 + ((row>>5)<<4) + (row&15) + (((row>>4)&1)<<8)
//  wout [L][256][256] fp32 -> Wob same layout bf16
// ---------------------------------------------------------------------------
__global__ void repack_w(const float* __restrict__ wc, const float* __restrict__ wo,
                         unsigned short* __restrict__ Wb, unsigned short* __restrict__ Wob) {
  size_t g = (size_t)blockIdx.x * 256 + threadIdx.x;
  const size_t NA = (size_t)LAYERS * 3 * 4 * 128 * 256;
  if (g < NA) {
    int c   = (int)(g & 255);
    int row = (int)((g >> 8) & 127);
    int y   = (int)((g >> 15) & 3);
    int lt  = (int)(g >> 17);           // l*3 + tap
    int tap = lt % 3, l = lt / 3;
    int ch = y * 64 + ((row >> 5) << 4) + (row & 15) + (((row >> 4) & 1) << 8);
    Wb[g] = f2b(wc[(((size_t)l * 512 + ch) * 256 + c) * 3 + tap]);
  } else {
    size_t g2 = g - NA;
    if (g2 < (size_t)LAYERS * 256 * 256) Wob[g2] = f2b(wo[g2]);
  }
}

// ---------------------------------------------------------------------------
// Zero the causal pad rows of xTb (workspace is poisoned to 0xAA each call).
// ---------------------------------------------------------------------------
__global__ void zero_pads(unsigned short* __restrict__ xTb) {
  size_t off = (size_t)blockIdx.y * TROWS * CCH;
  int i = blockIdx.x * 256 + threadIdx.x;     // 128*256 = 32768 threads * 16 B = 512 KB
  ulonglong2 z; z.x = 0ull; z.y = 0ull;
  ((ulonglong2*)(xTb + off))[i] = z;
}

// ---------------------------------------------------------------------------
// Transpose input [B][C][T] fp32 -> xT [B][T][C] fp32  AND  xTb bf16 (padded)
// ---------------------------------------------------------------------------
__global__ void transpose_in(const float* __restrict__ in, float* __restrict__ xT,
                             unsigned short* __restrict__ xTb) {
  __shared__ float tile[32][33];
  const int tid = threadIdx.x;
  const int t0 = blockIdx.x * 32, c0 = blockIdx.y * 32, b = blockIdx.z;
#pragma unroll
  for (int q = 0; q < 4; ++q) {
    int e = tid + 256 * q; int r = e >> 5, cc = e & 31;   // r = c-local, cc = t-local
    tile[r][cc] = in[((size_t)b * CCH + c0 + r) * TLEN + t0 + cc];
  }
  __syncthreads();
#pragma unroll
  for (int q = 0; q < 4; ++q) {
    int e = tid + 256 * q; int r = e >> 5, cc = e & 31;   // r = t-local, cc = c-local
    float v = tile[cc][r];
    xT[((size_t)b * TLEN + t0 + r) * CCH + c0 + cc] = v;
    xTb[((size_t)b * TROWS + TPAD + t0 + r) * CCH + c0 + cc] = f2b(v);
  }
}

// ---------------------------------------------------------------------------
// Final: out[B][C][T] = xT[B][T][C] + hT(bf16)[B][T][C]   (last layer residual)
// ---------------------------------------------------------------------------
__global__ void final_addT(const float* __restrict__ xT, const unsigned short* __restrict__ hT,
                           float* __restrict__ out) {
  __shared__ float tile[32][33];
  const int tid = threadIdx.x;
  const int t0 = blockIdx.x * 32, c0 = blockIdx.y * 32, b = blockIdx.z;
#pragma unroll
  for (int q = 0; q < 4; ++q) {
    int e = tid + 256 * q; int r = e >> 5, cc = e & 31;   // r = t-local, cc = c-local
    size_t idx = ((size_t)b * TLEN + t0 + r) * CCH + c0 + cc;
    tile[r][cc] = xT[idx] + b2f(hT[idx]);
  }
  __syncthreads();
#pragma unroll
  for (int q = 0; q < 4; ++q) {
    int e = tid + 256 * q; int r = e >> 5, cc = e & 31;   // r = c-local, cc = t-local
    out[((size_t)b * CCH + c0 + r) * TLEN + t0 + cc] = tile[cc][r];
  }
}

// ---------------------------------------------------------------------------
// Dilated causal conv + gate.  Z^T tile (m=time, n=channel), K = 3*256.
// A from xTb (bf16, zero-padded rows -> no causal predicate), B from
// pre-interleaved Wb.  All staging via global_load_lds width=16.
// ---------------------------------------------------------------------------
__global__ __launch_bounds__(256)
void conv_gate_kernel(const unsigned short* __restrict__ xTb, // [B][TROWS][C] bf16
                      const unsigned short* __restrict__ Wl,  // [3][4][128][256] bf16, this layer
                      const float* __restrict__ bias,         // [512] fp32
                      unsigned short* __restrict__ hT,        // [B][T][C] bf16
                      float* __restrict__ skip,               // [B][C][T] fp32, this layer
                      int d) {
  __shared__ unsigned short As[128 * 32];  // [m=t][k], rows 64 B, unpadded (gload16)
  __shared__ unsigned short Bs[128 * 32];  // [n=row][k]

  const int tid  = threadIdx.x;
  const int lane = tid & 63;
  const int wv   = tid >> 6;
  const int wm   = wv & 1, wn = wv >> 1;
  const int col  = lane & 15, quad = lane >> 4;

  const int t0 = blockIdx.x * 128;
  const int y  = blockIdx.y;            // 64 gated channels per y
  const int o0 = y * 64;
  const int b  = blockIdx.z;

  const int rl = lane >> 2;             // staging row within 16-row chunk
  const int kl = (lane & 3) * 8;        // staging k-offset (shorts)
  const int ch0 = wv * 2;               // this wave's first 16-row chunk

  f32x4 acc[4][4];
  const f32x4 zero = {0.f, 0.f, 0.f, 0.f};
#pragma unroll
  for (int i = 0; i < 4; ++i)
#pragma unroll
    for (int j = 0; j < 4; ++j) acc[i][j] = zero;

  for (int tap = 0; tap < 3; ++tap) {
    const int s = (2 - tap) * d;                      // causal shift: x[t - s]
    const unsigned short* Ab = xTb + ((size_t)b * TROWS + TPAD + t0 - s) * CCH;
    const unsigned short* Wb = Wl + ((size_t)tap * 4 + y) * 128 * 256;
    for (int c0 = 0; c0 < 256; c0 += 32) {
      __syncthreads();
      gload16(Ab + (size_t)(ch0 * 16      + rl) * CCH + c0 + kl, &As[ ch0      * 512]);
      gload16(Ab + (size_t)(ch0 * 16 + 16 + rl) * CCH + c0 + kl, &As[(ch0 + 1) * 512]);
      gload16(Wb + (size_t)(ch0 * 16      + rl) * 256 + c0 + kl, &Bs[ ch0      * 512]);
      gload16(Wb + (size_t)(ch0 * 16 + 16 + rl) * 256 + c0 + kl, &Bs[(ch0 + 1) * 512]);
      __syncthreads();
      const int k0 = quad * 8;
      bf16x8 af[4], bfv[4];
#pragma unroll
      for (int mf = 0; mf < 4; ++mf)
        af[mf] = *(const bf16x8*)&As[(wm * 64 + mf * 16 + col) * 32 + k0];
#pragma unroll
      for (int nf = 0; nf < 4; ++nf)
        bfv[nf] = *(const bf16x8*)&Bs[(wn * 64 + nf * 16 + col) * 32 + k0];
#pragma unroll
      for (int mf = 0; mf < 4; ++mf)
#pragma unroll
        for (int nf = 0; nf < 4; ++nf)
          acc[mf][nf] = __builtin_amdgcn_mfma_f32_16x16x32_bf16(af[mf], bfv[nf], acc[mf][nf], 0, 0, 0);
    }
  }

  // ---- epilogue: bias, gate, store hT (bf16, [t][c]) and skip (fp32, [c][t])
#pragma unroll
  for (int mf = 0; mf < 4; ++mf) {
    const int tb = t0 + wm * 64 + mf * 16 + quad * 4;
#pragma unroll
    for (int p = 0; p < 2; ++p) {
      const int pair = wn * 2 + p;
      const int ch = o0 + pair * 16 + col;       // gated output channel (0..255)
      const float btop = bias[ch];
      const float bbot = bias[ch + 256];
      f32x4 zt = acc[mf][2 * p];
      f32x4 zb = acc[mf][2 * p + 1];
      float hr[4];
#pragma unroll
      for (int r = 0; r < 4; ++r) {
        float h = fast_tanh(zt[r] + btop) * fast_sigmoid(zb[r] + bbot);
        hr[r] = h;
        hT[((size_t)b * TLEN + tb + r) * CCH + ch] = f2b(h);
      }
      float4 hv; hv.x = hr[0]; hv.y = hr[1]; hv.z = hr[2]; hv.w = hr[3];
      *(float4*)&skip[((size_t)b * CCH + ch) * TLEN + tb] = hv;
    }
  }
}

// ---------------------------------------------------------------------------
// 1x1 transform + residual (in-place on xT, also refreshes bf16 copy xTb):
//   xT[b][t][o] += sum_c Wo[o][c] * h[b][t][c] + bout[o]
// ---------------------------------------------------------------------------
__global__ __launch_bounds__(256)
void onexone_kernel(const unsigned short* __restrict__ hT,  // [B][T][C] bf16
                    const unsigned short* __restrict__ Wo,  // [256][256] bf16, this layer
                    const float* __restrict__ bias,         // [256]
                    float* __restrict__ xT,                 // [B][T][C] fp32, in-place
                    unsigned short* __restrict__ xTb) {     // [B][TROWS][C] bf16
  __shared__ unsigned short As[128 * 32];
  __shared__ unsigned short Bs[128 * 32];

  const int tid  = threadIdx.x;
  const int lane = tid & 63;
  const int wv   = tid >> 6;
  const int wm   = wv & 1, wn = wv >> 1;
  const int col  = lane & 15, quad = lane >> 4;

  const int t0 = blockIdx.x * 128;
  const int o0 = blockIdx.y * 128;
  const int b  = blockIdx.z;

  const int rl = lane >> 2;
  const int kl = (lane & 3) * 8;
  const int ch0 = wv * 2;

  const unsigned short* Ab = hT + (size_t)b * TLEN * CCH + (size_t)t0 * CCH;
  const unsigned short* Wb = Wo + (size_t)o0 * 256;

  f32x4 acc[4][4];
  const f32x4 zero = {0.f, 0.f, 0.f, 0.f};
#pragma unroll
  for (int i = 0; i < 4; ++i)
#pragma unroll
    for (int j = 0; j < 4; ++j) acc[i][j] = zero;

  for (int c0 = 0; c0 < 256; c0 += 32) {
    __syncthreads();
    gload16(Ab + (size_t)(ch0 * 16      + rl) * CCH + c0 + kl, &As[ ch0      * 512]);
    gload16(Ab + (size_t)(ch0 * 16 + 16 + rl) * CCH + c0 + kl, &As[(ch0 + 1) * 512]);
    gload16(Wb + (size_t)(ch0 * 16      + rl) * 256 + c0 + kl, &Bs[ ch0      * 512]);
    gload16(Wb + (size_t)(ch0 * 16 + 16 + rl) * 256 + c0 + kl, &Bs[(ch0 + 1) * 512]);
    __syncthreads();
    const int k0 = quad * 8;
    bf16x8 af[4], bfv[4];
#pragma unroll
    for (int mf = 0; mf < 4; ++mf)
      af[mf] = *(const bf16x8*)&As[(wm * 64 + mf * 16 + col) * 32 + k0];
#pragma unroll
    for (int nf = 0; nf < 4; ++nf)
      bfv[nf] = *(const bf16x8*)&Bs[(wn * 64 + nf * 16 + col) * 32 + k0];
#pragma unroll
    for (int mf = 0; mf < 4; ++mf)
#pragma unroll
      for (int nf = 0; nf < 4; ++nf)
        acc[mf][nf] = __builtin_amdgcn_mfma_f32_16x16x32_bf16(af[mf], bfv[nf], acc[mf][nf], 0, 0, 0);
  }

#pragma unroll
  for (int mf = 0; mf < 4; ++mf) {
    const int tb = t0 + wm * 64 + mf * 16 + quad * 4;
#pragma unroll
    for (int nf = 0; nf < 4; ++nf) {
      const int ch = o0 + wn * 64 + nf * 16 + col;
      const float bo = bias[ch];
#pragma unroll
      for (int r = 0; r < 4; ++r) {
        size_t idx = ((size_t)b * TLEN + tb + r) * CCH + ch;
        float nv = xT[idx] + acc[mf][nf][r] + bo;
        xT[idx] = nv;
        xTb[((size_t)b * TROWS + TPAD + tb + r) * CCH + ch] = f2b(nv);
      }
    }
  }
}

// ---------------------------------------------------------------------------
extern "C" void kernel_launch(void* const* d_in, const int* in_sizes, int n_in,
                              void* d_out, int out_size, void* d_ws, size_t ws_size,
                              hipStream_t stream) {
  const float* input = (const float*)d_in[0];
  const float* wconv = (const float*)d_in[1];
  const float* bconv = (const float*)d_in[2];
  const float* wout  = (const float*)d_in[3];
  const float* bout  = (const float*)d_in[4];
  float* out   = (float*)d_out;
  float* skips = out + (size_t)BCT;        // [L][B][C][T]

  char* ws = (char*)d_ws;
  float*          xT  = (float*)ws;                                    // BCT fp32
  unsigned short* xTb = (unsigned short*)(ws + (size_t)BCT * 4);       // B*TROWS*C bf16
  unsigned short* hT  = (unsigned short*)(ws + (size_t)BCT * 4
                                             + (size_t)BATCH * TROWS * CCH * 2);
  unsigned short* Wb  = hT + (size_t)BCT;                              // L*3*4*128*256
  unsigned short* Wob = Wb + (size_t)LAYERS * 3 * 512 * 256;           // L*256*256

  static const int dil[LAYERS] = {1, 2, 4, 8, 16, 32, 64, 128, 256, 512};

  repack_w<<<17920, 256, 0, stream>>>(wconv, wout, Wb, Wob);
  zero_pads<<<dim3(128, BATCH), 256, 0, stream>>>(xTb);
  transpose_in<<<dim3(TLEN / 32, CCH / 32, BATCH), 256, 0, stream>>>(input, xT, xTb);

  for (int l = 0; l < LAYERS; ++l) {
    conv_gate_kernel<<<dim3(TLEN / 128, 4, BATCH), 256, 0, stream>>>(
        xTb, Wb + (size_t)l * 3 * 512 * 256, bconv + (size_t)l * 512,
        hT, skips + (size_t)l * BCT, dil[l]);
    if (l < LAYERS - 1) {
      onexone_kernel<<<dim3(TLEN / 128, 2, BATCH), 256, 0, stream>>>(
          hT, Wob + (size_t)l * 256 * 256, bout + (size_t)l * 256, xT, xTb);
    } else {
      final_addT<<<dim3(TLEN / 32, CCH / 32, BATCH), 256, 0, stream>>>(xT, hT, out);
    }
  }
}